// Round 1
// baseline (421.739 us; speedup 1.0000x reference)
//
#include <hip/hip_runtime.h>
#include <hip/hip_bf16.h>

#define B_  16
#define T_  128
#define D_  64
#define NF_ 32
#define TS_ 64
#define H_  128

using bf16x8 = __attribute__((ext_vector_type(8))) short;
using f32x4  = __attribute__((ext_vector_type(4))) float;

// ---------- helpers ----------
__device__ __forceinline__ unsigned short f2bf(float x) {
    union { float f; unsigned int u; } v; v.f = x;
    unsigned int u = v.u;
    unsigned int r = (u + 0x7fffu + ((u >> 16) & 1u)) >> 16;   // RTNE
    return (unsigned short)r;
}
__device__ __forceinline__ float sigm(float x) {
    return 1.0f / (1.0f + __expf(-x));
}
__device__ __forceinline__ float tanhfast(float x) {
    float e = __expf(-2.0f * fabsf(x));       // e in (0,1], no overflow
    float t = (1.0f - e) / (1.0f + e);
    return copysignf(t, x);
}

// ---------- K1: xs = tanh(X @ W_t^T + b_t), written as bf16 in MFMA A-frag-linear layout ----------
// xs tile for (group g of 16 rows, t): 1024 bf16 elems; elem(r, ts) at
//   (ts>>5)*512 + ((ts&31)>>3)*128 + r*8 + (ts&7)      [lane*8+b within K-tile]
__global__ __launch_bounds__(256) void k_proj(const float* __restrict__ X,
                                              const float* __restrict__ Wt,
                                              const float* __restrict__ bt,
                                              unsigned short* __restrict__ xs)
{
    __shared__ float sW[TS_ * NF_];
    __shared__ float sb[TS_];
    __shared__ float sX[16 * NF_];
    int g = blockIdx.x, t = blockIdx.y, tid = threadIdx.x;

    for (int i = tid; i < TS_ * NF_; i += 256) sW[i] = Wt[i];
    if (tid < TS_) sb[tid] = bt[tid];
    for (int i = tid; i < 16 * NF_; i += 256) {
        int r = i >> 5, nf = i & 31;
        int bp = g * 16 + r, b = bp >> 6, d = bp & 63;
        sX[i] = X[(((size_t)b * T_ + t) * D_ + d) * NF_ + nf];
    }
    __syncthreads();

    size_t tile = ((size_t)(g * T_ + t)) * 1024;
    for (int idx = tid; idx < 1024; idx += 256) {
        int r = idx >> 6, ts = idx & 63;
        float s = sb[ts];
        const float* w  = &sW[ts * NF_];
        const float* xr = &sX[r * NF_];
        #pragma unroll
        for (int nf = 0; nf < NF_; ++nf) s += xr[nf] * w[nf];
        float v = tanhfast(s);
        int off = ((ts >> 5) << 9) + (((ts & 31) >> 3) << 7) + (r << 3) + (ts & 7);
        xs[tile + off] = f2bf(v);
    }
}

// ---------- K2: bidirectional (two independent forward-time) LSTM, MFMA recurrent GEMM ----------
// 128 blocks: blockIdx = g (0..63) | dir<<6. 512 threads = 8 waves.
// Wave w owns h-cols j = 16w..16w+15; gate col-tiles {j, 128+j, 256+j, 384+j}.
// B-frags (Whh 4x4, Wih 4x2) resident in VGPRs. h exchanged via 4KB frag-linear LDS.
__global__ __launch_bounds__(512, 2) void k_lstm(
    const unsigned short* __restrict__ xs,
    const float* __restrict__ WihF, const float* __restrict__ WhhF,
    const float* __restrict__ bihF, const float* __restrict__ bhhF,
    const float* __restrict__ WihB, const float* __restrict__ WhhB,
    const float* __restrict__ bihB, const float* __restrict__ bhhB,
    float* __restrict__ hvec)
{
    __shared__ __align__(16) unsigned short hl[2048];   // 4 K-tiles * 64 lanes * 8 bf16

    int g = blockIdx.x & 63, dir = blockIdx.x >> 6;
    int tid = threadIdx.x, wid = tid >> 6, lane = tid & 63;
    int lhi = lane >> 4, llo = lane & 15;

    const float* Wih = dir ? WihB : WihF;
    const float* Whh = dir ? WhhB : WhhF;
    const float* bih = dir ? bihB : bihF;
    const float* bhh = dir ? bhhB : bhhF;

    int jb = wid << 4;
    bf16x8 whh[4][4], wih[4][2];
    float bias[4];
    #pragma unroll
    for (int gt = 0; gt < 4; ++gt) {
        int n = gt * H_ + jb + llo;               // gate row (col of B)
        bias[gt] = bih[n] + bhh[n];
        const float* wr = Whh + (size_t)n * H_;
        #pragma unroll
        for (int kt = 0; kt < 4; ++kt) {
            const float* p = wr + kt * 32 + lhi * 8;
            bf16x8 v;
            #pragma unroll
            for (int e = 0; e < 8; ++e) v[e] = (short)f2bf(p[e]);
            whh[gt][kt] = v;
        }
        const float* wr2 = Wih + (size_t)n * TS_;
        #pragma unroll
        for (int kt = 0; kt < 2; ++kt) {
            const float* p = wr2 + kt * 32 + lhi * 8;
            bf16x8 v;
            #pragma unroll
            for (int e = 0; e < 8; ++e) v[e] = (short)f2bf(p[e]);
            wih[gt][kt] = v;
        }
    }

    for (int i = tid; i < 1024; i += 512) ((unsigned int*)hl)[i] = 0u;   // h0 = 0

    float c[4] = {0.f, 0.f, 0.f, 0.f};
    int j = jb + llo;                                    // this lane's h index
    int jelem = ((j >> 5) << 9) + (((j & 31) >> 3) << 7) + (j & 7);  // + r*8
    int r0 = lhi * 4;
    const unsigned short* xsg = xs + ((size_t)g * T_) * 1024;
    __syncthreads();

    for (int t = 0; t < T_; ++t) {
        bf16x8 ax0 = *(const bf16x8*)(xsg + (size_t)t * 1024 + lane * 8);
        bf16x8 ax1 = *(const bf16x8*)(xsg + (size_t)t * 1024 + 512 + lane * 8);
        bf16x8 ah[4];
        #pragma unroll
        for (int kt = 0; kt < 4; ++kt)
            ah[kt] = *(const bf16x8*)(hl + kt * 512 + lane * 8);

        f32x4 acc[4];
        #pragma unroll
        for (int gt = 0; gt < 4; ++gt) {
            f32x4 a = {bias[gt], bias[gt], bias[gt], bias[gt]};
            #pragma unroll
            for (int kt = 0; kt < 4; ++kt)
                a = __builtin_amdgcn_mfma_f32_16x16x32_bf16(ah[kt], whh[gt][kt], a, 0, 0, 0);
            a = __builtin_amdgcn_mfma_f32_16x16x32_bf16(ax0, wih[gt][0], a, 0, 0, 0);
            a = __builtin_amdgcn_mfma_f32_16x16x32_bf16(ax1, wih[gt][1], a, 0, 0, 0);
            acc[gt] = a;
        }

        float hv[4];
        #pragma unroll
        for (int s = 0; s < 4; ++s) {
            float iv = sigm(acc[0][s]);
            float fv = sigm(acc[1][s]);
            float gv = tanhfast(acc[2][s]);
            float ov = sigm(acc[3][s]);
            float cn = fv * c[s] + iv * gv;
            c[s] = cn;
            hv[s] = ov * tanhfast(cn);
        }

        #pragma unroll
        for (int s = 0; s < 4; ++s) {
            int bp = g * 16 + r0 + s;
            hvec[((size_t)bp * T_ + t) * 256 + dir * H_ + j] = hv[s];
        }

        __syncthreads();                         // everyone done reading old h
        #pragma unroll
        for (int s = 0; s < 4; ++s) hl[jelem + (r0 + s) * 8] = f2bf(hv[s]);
        __syncthreads();                         // new h visible
    }
}

// ---------- K3a: attention pooling per sequence row ----------
__global__ __launch_bounds__(128) void k_attn(const float* __restrict__ hvec,
                                              float* __restrict__ pooled)
{
    __shared__ float hT[256];
    __shared__ float sc[128];
    __shared__ float tmp[128];
    int bp = blockIdx.x, tid = threadIdx.x;

    hT[tid]       = hvec[((size_t)bp * T_ + 127) * 256 + tid];
    hT[tid + 128] = hvec[((size_t)bp * T_ + 127) * 256 + 128 + tid];
    __syncthreads();

    const float* row = hvec + ((size_t)bp * T_ + tid) * 256;
    float s = 0.f;
    #pragma unroll 8
    for (int e = 0; e < 256; ++e) s += row[e] * hT[e];
    sc[tid] = s; tmp[tid] = s;
    __syncthreads();
    for (int o = 64; o > 0; o >>= 1) {
        if (tid < o) tmp[tid] = fmaxf(tmp[tid], tmp[tid + o]);
        __syncthreads();
    }
    float m = tmp[0];
    __syncthreads();
    float e = __expf(sc[tid] - m);
    sc[tid] = e; tmp[tid] = e;
    __syncthreads();
    for (int o = 64; o > 0; o >>= 1) {
        if (tid < o) tmp[tid] += tmp[tid + o];
        __syncthreads();
    }
    float inv = 1.0f / tmp[0];

    const float* hb = hvec + ((size_t)bp * T_) * 256;
    #pragma unroll
    for (int half = 0; half < 2; ++half) {
        int e2 = half * 128 + tid;
        float a = 0.f;
        for (int tt = 0; tt < 128; ++tt) a += sc[tt] * hb[(size_t)tt * 256 + e2];
        pooled[(size_t)bp * 256 + e2] = a * inv;
    }
}

// ---------- K3b: layernorm(ddof=1) * diag_w + diag_b ----------
__global__ __launch_bounds__(256) void k_norm(const float* __restrict__ pooled,
                                              const float* __restrict__ dw,
                                              const float* __restrict__ db,
                                              float* __restrict__ out)
{
    __shared__ double rs[256], rq[256];
    int b = blockIdx.x, tid = threadIdx.x;
    const float* xp = pooled + (size_t)b * 16384;
    double s = 0.0, q = 0.0;
    for (int i = tid; i < 16384; i += 256) { double x = xp[i]; s += x; q += x * x; }
    rs[tid] = s; rq[tid] = q;
    __syncthreads();
    for (int o = 128; o > 0; o >>= 1) {
        if (tid < o) { rs[tid] += rs[tid + o]; rq[tid] += rq[tid + o]; }
        __syncthreads();
    }
    double N = 16384.0;
    double mean = rs[0] / N;
    double var = (rq[0] - N * mean * mean) / (N - 1.0);
    float m = (float)mean;
    float invs = (float)(1.0 / sqrt(var));
    for (int i = tid; i < 16384; i += 256) {
        float x = xp[i];
        out[(size_t)b * 16384 + i] = (x - m) * invs * dw[i] + db[i];
    }
}

// ---------- launch ----------
extern "C" void kernel_launch(void* const* d_in, const int* in_sizes, int n_in,
                              void* d_out, int out_size, void* d_ws, size_t ws_size,
                              hipStream_t stream)
{
    const float* X    = (const float*)d_in[0];
    const float* Wt   = (const float*)d_in[1];
    const float* bt   = (const float*)d_in[2];
    const float* WihF = (const float*)d_in[3];
    const float* WhhF = (const float*)d_in[4];
    const float* bihF = (const float*)d_in[5];
    const float* bhhF = (const float*)d_in[6];
    const float* WihB = (const float*)d_in[7];
    const float* WhhB = (const float*)d_in[8];
    const float* bihB = (const float*)d_in[9];
    const float* bhhB = (const float*)d_in[10];
    const float* dw   = (const float*)d_in[11];
    const float* db   = (const float*)d_in[12];
    float* out = (float*)d_out;

    char* ws = (char*)d_ws;
    unsigned short* xs = (unsigned short*)(ws);                       // 16 MiB bf16 frag-linear
    float* hvec   = (float*)(ws + 16777216);                          // 128 MiB fp32 (Bp,T,256)
    float* pooled = (float*)(ws + 16777216 + 134217728);              // 1 MiB fp32 (Bp,256)

    k_proj<<<dim3(64, 128), 256, 0, stream>>>(X, Wt, bt, xs);
    k_lstm<<<128, 512, 0, stream>>>(xs, WihF, WhhF, bihF, bhhF,
                                        WihB, WhhB, bihB, bhhB, hvec);
    k_attn<<<1024, 128, 0, stream>>>(hvec, pooled);
    k_norm<<<16, 256, 0, stream>>>(pooled, dw, db, out);
}

// Round 7
// 333.756 us; speedup vs baseline: 1.2636x; 1.2636x over previous
//
#include <hip/hip_runtime.h>
#include <hip/hip_bf16.h>

#define B_  16
#define T_  128
#define D_  64
#define NF_ 32
#define TS_ 64
#define H_  128

using bf16x8 = __attribute__((ext_vector_type(8))) short;
using f32x4  = __attribute__((ext_vector_type(4))) float;

// ---------- helpers ----------
__device__ __forceinline__ unsigned short f2bf(float x) {
    union { float f; unsigned int u; } v; v.f = x;
    unsigned int u = v.u;
    unsigned int r = (u + 0x7fffu + ((u >> 16) & 1u)) >> 16;   // RTNE
    return (unsigned short)r;
}
__device__ __forceinline__ float rcpf(float x) { return __builtin_amdgcn_rcpf(x); }
__device__ __forceinline__ float sigm(float x) {
    return rcpf(1.0f + __expf(-x));           // v_exp + v_rcp, ~1ulp
}
__device__ __forceinline__ float tanhfast(float x) {
    float e = __expf(-2.0f * fabsf(x));       // e in (0,1], no overflow
    float t = (1.0f - e) * rcpf(1.0f + e);
    return copysignf(t, x);
}

// ---------- K1: xs = tanh(X @ W_t^T + b_t), written as bf16 in MFMA A-frag-linear layout ----------
// xs tile for (group g of 16 rows, t): 1024 bf16 elems; elem(r, ts) at
//   (ts>>5)*512 + ((ts&31)>>3)*128 + r*8 + (ts&7)
__global__ __launch_bounds__(256) void k_proj(const float* __restrict__ X,
                                              const float* __restrict__ Wt,
                                              const float* __restrict__ bt,
                                              unsigned short* __restrict__ xs)
{
    __shared__ float sW[TS_ * NF_];
    __shared__ float sb[TS_];
    __shared__ float sX[16 * NF_];
    int g = blockIdx.x, t = blockIdx.y, tid = threadIdx.x;

    for (int i = tid; i < TS_ * NF_; i += 256) sW[i] = Wt[i];
    if (tid < TS_) sb[tid] = bt[tid];
    for (int i = tid; i < 16 * NF_; i += 256) {
        int r = i >> 5, nf = i & 31;
        int bp = g * 16 + r, b = bp >> 6, d = bp & 63;
        sX[i] = X[(((size_t)b * T_ + t) * D_ + d) * NF_ + nf];
    }
    __syncthreads();

    size_t tile = ((size_t)(g * T_ + t)) * 1024;
    for (int idx = tid; idx < 1024; idx += 256) {
        int r = idx >> 6, ts = idx & 63;
        float s = sb[ts];
        const float* w  = &sW[ts * NF_];
        const float* xr = &sX[r * NF_];
        #pragma unroll
        for (int nf = 0; nf < NF_; ++nf) s += xr[nf] * w[nf];
        float v = tanhfast(s);
        int off = ((ts >> 5) << 9) + (((ts & 31) >> 3) << 7) + (r << 3) + (ts & 7);
        xs[tile + off] = f2bf(v);
    }
}

// ---------- K2: bidirectional LSTM, MFMA recurrent GEMM ----------
// 128 blocks: blockIdx = g (0..63) | dir<<6. 512 threads = 8 waves.
// Wave w owns h-cols j = 16w..16w+15; gate col-tiles {j, 128+j, 256+j, 384+j}.
// B-frags (Whh 4x4, Wih 4x2) resident in VGPRs.
// h double-buffered in LDS -> ONE raw barrier per step, lgkmcnt-only wait
// (global hvec stores are never drained inside the loop).
__global__ __launch_bounds__(512, 2) void k_lstm(
    const unsigned short* __restrict__ xs,
    const float* __restrict__ WihF, const float* __restrict__ WhhF,
    const float* __restrict__ bihF, const float* __restrict__ bhhF,
    const float* __restrict__ WihB, const float* __restrict__ WhhB,
    const float* __restrict__ bihB, const float* __restrict__ bhhB,
    float* __restrict__ hvec)
{
    __shared__ __align__(16) unsigned short hl[2][2048];   // double buffer, 4KB each

    int g = blockIdx.x & 63, dir = blockIdx.x >> 6;
    int tid = threadIdx.x, wid = tid >> 6, lane = tid & 63;
    int lhi = lane >> 4, llo = lane & 15;

    const float* Wih = dir ? WihB : WihF;
    const float* Whh = dir ? WhhB : WhhF;
    const float* bih = dir ? bihB : bihF;
    const float* bhh = dir ? bhhB : bhhF;

    int jb = wid << 4;
    bf16x8 whh[4][4], wih[4][2];
    float bias[4];
    #pragma unroll
    for (int gt = 0; gt < 4; ++gt) {
        int n = gt * H_ + jb + llo;               // gate row (col of B)
        bias[gt] = bih[n] + bhh[n];
        const float* wr = Whh + (size_t)n * H_;
        #pragma unroll
        for (int kt = 0; kt < 4; ++kt) {
            const float* p = wr + kt * 32 + lhi * 8;
            bf16x8 v;
            #pragma unroll
            for (int e = 0; e < 8; ++e) v[e] = (short)f2bf(p[e]);
            whh[gt][kt] = v;
        }
        const float* wr2 = Wih + (size_t)n * TS_;
        #pragma unroll
        for (int kt = 0; kt < 2; ++kt) {
            const float* p = wr2 + kt * 32 + lhi * 8;
            bf16x8 v;
            #pragma unroll
            for (int e = 0; e < 8; ++e) v[e] = (short)f2bf(p[e]);
            wih[gt][kt] = v;
        }
    }

    for (int i = tid; i < 1024; i += 512) ((unsigned int*)hl[0])[i] = 0u;   // h0 = 0

    float c[4] = {0.f, 0.f, 0.f, 0.f};
    int j = jb + llo;                                    // this lane's h index
    int jelem = ((j >> 5) << 9) + (((j & 31) >> 3) << 7) + (j & 7);  // + r*8
    int r0 = lhi * 4;
    const unsigned short* xsg = xs + ((size_t)g * T_) * 1024;

    asm volatile("s_waitcnt lgkmcnt(0)" ::: "memory");
    __builtin_amdgcn_s_barrier();
    __builtin_amdgcn_sched_barrier(0);

    // prefetch t=0 x-fragments
    bf16x8 nx0 = *(const bf16x8*)(xsg + lane * 8);
    bf16x8 nx1 = *(const bf16x8*)(xsg + 512 + lane * 8);

    int cur = 0;
    for (int t = 0; t < T_; ++t) {
        bf16x8 ax0 = nx0, ax1 = nx1;
        int tn = (t < T_ - 1) ? t + 1 : t;
        nx0 = *(const bf16x8*)(xsg + (size_t)tn * 1024 + lane * 8);
        nx1 = *(const bf16x8*)(xsg + (size_t)tn * 1024 + 512 + lane * 8);

        bf16x8 ah[4];
        #pragma unroll
        for (int kt = 0; kt < 4; ++kt)
            ah[kt] = *(const bf16x8*)(hl[cur] + kt * 512 + lane * 8);

        f32x4 acc[4];
        #pragma unroll
        for (int gt = 0; gt < 4; ++gt) {
            f32x4 a = {bias[gt], bias[gt], bias[gt], bias[gt]};
            a = __builtin_amdgcn_mfma_f32_16x16x32_bf16(ax0, wih[gt][0], a, 0, 0, 0);
            a = __builtin_amdgcn_mfma_f32_16x16x32_bf16(ax1, wih[gt][1], a, 0, 0, 0);
            #pragma unroll
            for (int kt = 0; kt < 4; ++kt)
                a = __builtin_amdgcn_mfma_f32_16x16x32_bf16(ah[kt], whh[gt][kt], a, 0, 0, 0);
            acc[gt] = a;
        }

        float hv[4];
        #pragma unroll
        for (int s = 0; s < 4; ++s) {
            float iv = sigm(acc[0][s]);
            float fv = sigm(acc[1][s]);
            float gv = tanhfast(acc[2][s]);
            float ov = sigm(acc[3][s]);
            float cn = fv * c[s] + iv * gv;
            c[s] = cn;
            hv[s] = ov * tanhfast(cn);
        }

        int nxt = cur ^ 1;
        #pragma unroll
        for (int s = 0; s < 4; ++s) hl[nxt][jelem + (r0 + s) * 8] = f2bf(hv[s]);

        // fire-and-forget fp32 output (drains across future steps, no vmcnt here)
        #pragma unroll
        for (int s = 0; s < 4; ++s) {
            int bp = g * 16 + r0 + s;
            hvec[((size_t)bp * T_ + t) * 256 + dir * H_ + j] = hv[s];
        }

        asm volatile("s_waitcnt lgkmcnt(0)" ::: "memory");   // own LDS reads+writes done
        __builtin_amdgcn_s_barrier();                        // all waves' h[nxt] visible
        __builtin_amdgcn_sched_barrier(0);
        cur = nxt;
    }
}

// ---------- K3a: attention pooling, LDS-staged, coalesced ----------
__global__ __launch_bounds__(256, 1) void k_attn(const float* __restrict__ hvec,
                                                 float* __restrict__ pooled)
{
    __shared__ float sh[T_ * 256];    // 128 KB: whole (T,256) block
    __shared__ float sc[T_];
    int bp = blockIdx.x, tid = threadIdx.x;

    const float4* src = (const float4*)(hvec + (size_t)bp * T_ * 256);
    float4* dst = (float4*)sh;
    #pragma unroll
    for (int i = 0; i < 32; ++i) dst[tid + i * 256] = src[tid + i * 256];
    __syncthreads();

    int wid = tid >> 6, lane = tid & 63;
    float4 q = *(const float4*)&sh[127 * 256 + lane * 4];
    #pragma unroll 4
    for (int r = 0; r < 32; ++r) {
        int t = wid + r * 4;
        float4 hr = *(const float4*)&sh[t * 256 + lane * 4];
        float s = hr.x * q.x + hr.y * q.y + hr.z * q.z + hr.w * q.w;
        s += __shfl_xor(s, 32); s += __shfl_xor(s, 16); s += __shfl_xor(s, 8);
        s += __shfl_xor(s, 4);  s += __shfl_xor(s, 2);  s += __shfl_xor(s, 1);
        if (lane == 0) sc[t] = s;
    }
    __syncthreads();

    float m = -1e30f;
    for (int t2 = 0; t2 < T_; ++t2) m = fmaxf(m, sc[t2]);   // broadcast reads
    __syncthreads();
    if (tid < T_) sc[tid] = __expf(sc[tid] - m);
    __syncthreads();
    float ssum = 0.f;
    for (int t2 = 0; t2 < T_; ++t2) ssum += sc[t2];
    float inv = 1.0f / ssum;

    float a = 0.f;
    #pragma unroll 8
    for (int t2 = 0; t2 < T_; ++t2) a += sc[t2] * sh[t2 * 256 + tid];
    pooled[(size_t)bp * 256 + tid] = a * inv;
}

// ---------- K3b: layernorm(ddof=1) * diag_w + diag_b ----------
__global__ __launch_bounds__(256) void k_norm(const float* __restrict__ pooled,
                                              const float* __restrict__ dw,
                                              const float* __restrict__ db,
                                              float* __restrict__ out)
{
    __shared__ double rs[256], rq[256];
    int b = blockIdx.x, tid = threadIdx.x;
    const float* xp = pooled + (size_t)b * 16384;
    double s = 0.0, q = 0.0;
    for (int i = tid; i < 16384; i += 256) { double x = xp[i]; s += x; q += x * x; }
    rs[tid] = s; rq[tid] = q;
    __syncthreads();
    for (int o = 128; o > 0; o >>= 1) {
        if (tid < o) { rs[tid] += rs[tid + o]; rq[tid] += rq[tid + o]; }
        __syncthreads();
    }
    double N = 16384.0;
    double mean = rs[0] / N;
    double var = (rq[0] - N * mean * mean) / (N - 1.0);
    float m = (float)mean;
    float invs = (float)(1.0 / sqrt(var));
    for (int i = tid; i < 16384; i += 256) {
        float x = xp[i];
        out[(size_t)b * 16384 + i] = (x - m) * invs * dw[i] + db[i];
    }
}

// ---------- launch ----------
extern "C" void kernel_launch(void* const* d_in, const int* in_sizes, int n_in,
                              void* d_out, int out_size, void* d_ws, size_t ws_size,
                              hipStream_t stream)
{
    const float* X    = (const float*)d_in[0];
    const float* Wt   = (const float*)d_in[1];
    const float* bt   = (const float*)d_in[2];
    const float* WihF = (const float*)d_in[3];
    const float* WhhF = (const float*)d_in[4];
    const float* bihF = (const float*)d_in[5];
    const float* bhhF = (const float*)d_in[6];
    const float* WihB = (const float*)d_in[7];
    const float* WhhB = (const float*)d_in[8];
    const float* bihB = (const float*)d_in[9];
    const float* bhhB = (const float*)d_in[10];
    const float* dw   = (const float*)d_in[11];
    const float* db   = (const float*)d_in[12];
    float* out = (float*)d_out;

    char* ws = (char*)d_ws;
    unsigned short* xs = (unsigned short*)(ws);                       // 16 MiB bf16 frag-linear
    float* hvec   = (float*)(ws + 16777216);                          // 128 MiB fp32 (Bp,T,256)
    float* pooled = (float*)(ws + 16777216 + 134217728);              // 1 MiB fp32 (Bp,256)

    k_proj<<<dim3(64, 128), 256, 0, stream>>>(X, Wt, bt, xs);
    k_lstm<<<128, 512, 0, stream>>>(xs, WihF, WhhF, bihF, bhhF,
                                        WihB, WhhB, bihB, bhhB, hvec);
    k_attn<<<1024, 256, 0, stream>>>(hvec, pooled);
    k_norm<<<16, 256, 0, stream>>>(pooled, dw, db, out);
}

// Round 9
// 321.901 us; speedup vs baseline: 1.3102x; 1.0368x over previous
//
#include <hip/hip_runtime.h>
#include <hip/hip_bf16.h>

#define B_  16
#define T_  128
#define D_  64
#define NF_ 32
#define TS_ 64
#define H_  128

using bf16x8 = __attribute__((ext_vector_type(8))) short;
using bf16x4 = __attribute__((ext_vector_type(4))) short;
using f32x4  = __attribute__((ext_vector_type(4))) float;

// ---------- helpers ----------
__device__ __forceinline__ unsigned short f2bf(float x) {
    union { float f; unsigned int u; } v; v.f = x;
    unsigned int u = v.u;
    unsigned int r = (u + 0x7fffu + ((u >> 16) & 1u)) >> 16;   // RTNE
    return (unsigned short)r;
}
__device__ __forceinline__ float bf2f(unsigned short u) {
    union { unsigned int u; float f; } v; v.u = ((unsigned int)u) << 16;
    return v.f;
}
__device__ __forceinline__ float rcpf(float x) { return __builtin_amdgcn_rcpf(x); }
__device__ __forceinline__ float sigm(float x) {
    return rcpf(1.0f + __expf(-x));
}
__device__ __forceinline__ float tanhfast(float x) {
    float e = __expf(-2.0f * fabsf(x));
    float t = (1.0f - e) * rcpf(1.0f + e);
    return copysignf(t, x);
}

// ---------- K1: xs = tanh(X @ W_t^T + b_t), bf16, MFMA A-frag-linear layout ----------
// sWt transposed with pad 65: bank-conflict-free on stage (banks (nf+ts)%32 over nf)
// and on read (banks (nf+ts)%32 over lanes' ts).  [was: 32-way conflict every read]
__global__ __launch_bounds__(256) void k_proj(const float* __restrict__ X,
                                              const float* __restrict__ Wt,
                                              const float* __restrict__ bt,
                                              unsigned short* __restrict__ xs)
{
    __shared__ float sWt[NF_ * 65];
    __shared__ float sb[TS_];
    __shared__ float sX[16 * NF_];
    int g = blockIdx.x, t = blockIdx.y, tid = threadIdx.x;

    for (int i = tid; i < TS_ * NF_; i += 256) {
        int ts = i >> 5, nf = i & 31;
        sWt[nf * 65 + ts] = Wt[i];           // coalesced global read, conflict-free LDS write
    }
    if (tid < TS_) sb[tid] = bt[tid];
    for (int i = tid; i < 16 * NF_; i += 256) {
        int r = i >> 5, nf = i & 31;
        int bp = g * 16 + r, b = bp >> 6, d = bp & 63;
        sX[i] = X[(((size_t)b * T_ + t) * D_ + d) * NF_ + nf];
    }
    __syncthreads();

    size_t tile = ((size_t)(g * T_ + t)) * 1024;
    for (int idx = tid; idx < 1024; idx += 256) {
        int r = idx >> 6, ts = idx & 63;
        float s = sb[ts];
        const float* xr = &sX[r * NF_];      // broadcast (same addr across lanes)
        #pragma unroll
        for (int nf = 0; nf < NF_; ++nf) s += xr[nf] * sWt[nf * 65 + ts];
        float v = tanhfast(s);
        int off = ((ts >> 5) << 9) + (((ts & 31) >> 3) << 7) + (r << 3) + (ts & 7);
        xs[tile + off] = f2bf(v);
    }
}

// ---------- K2: bidirectional LSTM, MFMA recurrent GEMM ----------
// Sync protocol unchanged (race-screened R7): h double-buffered in LDS, ONE raw
// barrier per step, lgkmcnt-only wait; global stores free-floating.
// New: bf16 hvec stores (half write traffic), 3-way MFMA chain split (dep 6->2),
// strength-reduced store addressing.
__global__ __launch_bounds__(512, 2) void k_lstm(
    const unsigned short* __restrict__ xs,
    const float* __restrict__ WihF, const float* __restrict__ WhhF,
    const float* __restrict__ bihF, const float* __restrict__ bhhF,
    const float* __restrict__ WihB, const float* __restrict__ WhhB,
    const float* __restrict__ bihB, const float* __restrict__ bhhB,
    unsigned short* __restrict__ hvec)
{
    __shared__ __align__(16) unsigned short hl[2][2048];

    int g = blockIdx.x & 63, dir = blockIdx.x >> 6;
    int tid = threadIdx.x, wid = tid >> 6, lane = tid & 63;
    int lhi = lane >> 4, llo = lane & 15;

    const float* Wih = dir ? WihB : WihF;
    const float* Whh = dir ? WhhB : WhhF;
    const float* bih = dir ? bihB : bihF;
    const float* bhh = dir ? bhhB : bhhF;

    int jb = wid << 4;
    bf16x8 whh[4][4], wih[4][2];
    float bias[4];
    #pragma unroll
    for (int gt = 0; gt < 4; ++gt) {
        int n = gt * H_ + jb + llo;
        bias[gt] = bih[n] + bhh[n];
        const float* wr = Whh + (size_t)n * H_;
        #pragma unroll
        for (int kt = 0; kt < 4; ++kt) {
            const float* p = wr + kt * 32 + lhi * 8;
            bf16x8 v;
            #pragma unroll
            for (int e = 0; e < 8; ++e) v[e] = (short)f2bf(p[e]);
            whh[gt][kt] = v;
        }
        const float* wr2 = Wih + (size_t)n * TS_;
        #pragma unroll
        for (int kt = 0; kt < 2; ++kt) {
            const float* p = wr2 + kt * 32 + lhi * 8;
            bf16x8 v;
            #pragma unroll
            for (int e = 0; e < 8; ++e) v[e] = (short)f2bf(p[e]);
            wih[gt][kt] = v;
        }
    }

    for (int i = tid; i < 1024; i += 512) ((unsigned int*)hl[0])[i] = 0u;

    float c[4] = {0.f, 0.f, 0.f, 0.f};
    int j = jb + llo;
    int jelem = ((j >> 5) << 9) + (((j & 31) >> 3) << 7) + (j & 7);
    int r0 = lhi * 4;
    const unsigned short* xsg = xs + ((size_t)g * T_) * 1024;
    // running hvec offset: row (g*16+r0), t=0, col dir*128+j; +=256 per step; +s*T_*256 per s
    size_t rowoff = ((size_t)(g * 16 + r0) * T_) * 256 + dir * H_ + j;

    asm volatile("s_waitcnt lgkmcnt(0)" ::: "memory");
    __builtin_amdgcn_s_barrier();
    __builtin_amdgcn_sched_barrier(0);

    bf16x8 nx0 = *(const bf16x8*)(xsg + lane * 8);
    bf16x8 nx1 = *(const bf16x8*)(xsg + 512 + lane * 8);

    int cur = 0;
    for (int t = 0; t < T_; ++t) {
        bf16x8 ax0 = nx0, ax1 = nx1;
        int tn = (t < T_ - 1) ? t + 1 : t;
        nx0 = *(const bf16x8*)(xsg + (size_t)tn * 1024 + lane * 8);
        nx1 = *(const bf16x8*)(xsg + (size_t)tn * 1024 + 512 + lane * 8);

        bf16x8 ah[4];
        #pragma unroll
        for (int kt = 0; kt < 4; ++kt)
            ah[kt] = *(const bf16x8*)(hl[cur] + kt * 512 + lane * 8);

        f32x4 acc[4];
        #pragma unroll
        for (int gt = 0; gt < 4; ++gt) {
            // 3 independent chains of depth 2 (was one chain of depth 6)
            f32x4 aX = {bias[gt], bias[gt], bias[gt], bias[gt]};
            aX = __builtin_amdgcn_mfma_f32_16x16x32_bf16(ax0, wih[gt][0], aX, 0, 0, 0);
            aX = __builtin_amdgcn_mfma_f32_16x16x32_bf16(ax1, wih[gt][1], aX, 0, 0, 0);
            f32x4 aH1 = {0.f, 0.f, 0.f, 0.f};
            aH1 = __builtin_amdgcn_mfma_f32_16x16x32_bf16(ah[0], whh[gt][0], aH1, 0, 0, 0);
            aH1 = __builtin_amdgcn_mfma_f32_16x16x32_bf16(ah[1], whh[gt][1], aH1, 0, 0, 0);
            f32x4 aH2 = {0.f, 0.f, 0.f, 0.f};
            aH2 = __builtin_amdgcn_mfma_f32_16x16x32_bf16(ah[2], whh[gt][2], aH2, 0, 0, 0);
            aH2 = __builtin_amdgcn_mfma_f32_16x16x32_bf16(ah[3], whh[gt][3], aH2, 0, 0, 0);
            acc[gt] = aX + aH1 + aH2;
        }

        float hv[4];
        #pragma unroll
        for (int s = 0; s < 4; ++s) {
            float iv = sigm(acc[0][s]);
            float fv = sigm(acc[1][s]);
            float gv = tanhfast(acc[2][s]);
            float ov = sigm(acc[3][s]);
            float cn = fv * c[s] + iv * gv;
            c[s] = cn;
            hv[s] = ov * tanhfast(cn);
        }

        int nxt = cur ^ 1;
        unsigned short hb[4];
        #pragma unroll
        for (int s = 0; s < 4; ++s) hb[s] = f2bf(hv[s]);
        #pragma unroll
        for (int s = 0; s < 4; ++s) hl[nxt][jelem + (r0 + s) * 8] = hb[s];

        // fire-and-forget bf16 output (never drained inside the loop)
        #pragma unroll
        for (int s = 0; s < 4; ++s)
            hvec[rowoff + (size_t)s * (T_ * 256)] = hb[s];
        rowoff += 256;

        asm volatile("s_waitcnt lgkmcnt(0)" ::: "memory");
        __builtin_amdgcn_s_barrier();
        __builtin_amdgcn_sched_barrier(0);
        cur = nxt;
    }
}

// ---------- K3a: attention pooling, bf16 hvec, LDS-staged ----------
__global__ __launch_bounds__(256) void k_attn(const unsigned short* __restrict__ hvec,
                                              float* __restrict__ pooled)
{
    __shared__ unsigned short sh[T_ * 256];   // 64 KB
    __shared__ float sc[T_];
    int bp = blockIdx.x, tid = threadIdx.x;

    const bf16x8* src = (const bf16x8*)(hvec + (size_t)bp * T_ * 256);
    bf16x8* dst = (bf16x8*)sh;
    #pragma unroll
    for (int i = 0; i < 16; ++i) dst[tid + i * 256] = src[tid + i * 256];
    __syncthreads();

    int wid = tid >> 6, lane = tid & 63;
    bf16x4 q4 = *(const bf16x4*)&sh[127 * 256 + lane * 4];
    float q0 = bf2f((unsigned short)q4[0]), q1 = bf2f((unsigned short)q4[1]);
    float q2 = bf2f((unsigned short)q4[2]), q3 = bf2f((unsigned short)q4[3]);
    #pragma unroll 4
    for (int r = 0; r < 32; ++r) {
        int t = wid + r * 4;
        bf16x4 h4 = *(const bf16x4*)&sh[t * 256 + lane * 4];
        float s = bf2f((unsigned short)h4[0]) * q0 + bf2f((unsigned short)h4[1]) * q1
                + bf2f((unsigned short)h4[2]) * q2 + bf2f((unsigned short)h4[3]) * q3;
        s += __shfl_xor(s, 32); s += __shfl_xor(s, 16); s += __shfl_xor(s, 8);
        s += __shfl_xor(s, 4);  s += __shfl_xor(s, 2);  s += __shfl_xor(s, 1);
        if (lane == 0) sc[t] = s;
    }
    __syncthreads();

    float m = -1e30f;
    for (int t2 = 0; t2 < T_; ++t2) m = fmaxf(m, sc[t2]);
    __syncthreads();
    if (tid < T_) sc[tid] = __expf(sc[tid] - m);
    __syncthreads();
    float ssum = 0.f;
    for (int t2 = 0; t2 < T_; ++t2) ssum += sc[t2];
    float inv = 1.0f / ssum;

    float a = 0.f;
    #pragma unroll 8
    for (int t2 = 0; t2 < T_; ++t2) a += sc[t2] * bf2f(sh[t2 * 256 + tid]);
    pooled[(size_t)bp * 256 + tid] = a * inv;
}

// ---------- K3b: layernorm(ddof=1) * diag_w + diag_b ----------
__global__ __launch_bounds__(256) void k_norm(const float* __restrict__ pooled,
                                              const float* __restrict__ dw,
                                              const float* __restrict__ db,
                                              float* __restrict__ out)
{
    __shared__ double rs[256], rq[256];
    int b = blockIdx.x, tid = threadIdx.x;
    const float* xp = pooled + (size_t)b * 16384;
    double s = 0.0, q = 0.0;
    for (int i = tid; i < 16384; i += 256) { double x = xp[i]; s += x; q += x * x; }
    rs[tid] = s; rq[tid] = q;
    __syncthreads();
    for (int o = 128; o > 0; o >>= 1) {
        if (tid < o) { rs[tid] += rs[tid + o]; rq[tid] += rq[tid + o]; }
        __syncthreads();
    }
    double N = 16384.0;
    double mean = rs[0] / N;
    double var = (rq[0] - N * mean * mean) / (N - 1.0);
    float m = (float)mean;
    float invs = (float)(1.0 / sqrt(var));
    for (int i = tid; i < 16384; i += 256) {
        float x = xp[i];
        out[(size_t)b * 16384 + i] = (x - m) * invs * dw[i] + db[i];
    }
}

// ---------- launch ----------
extern "C" void kernel_launch(void* const* d_in, const int* in_sizes, int n_in,
                              void* d_out, int out_size, void* d_ws, size_t ws_size,
                              hipStream_t stream)
{
    const float* X    = (const float*)d_in[0];
    const float* Wt   = (const float*)d_in[1];
    const float* bt   = (const float*)d_in[2];
    const float* WihF = (const float*)d_in[3];
    const float* WhhF = (const float*)d_in[4];
    const float* bihF = (const float*)d_in[5];
    const float* bhhF = (const float*)d_in[6];
    const float* WihB = (const float*)d_in[7];
    const float* WhhB = (const float*)d_in[8];
    const float* bihB = (const float*)d_in[9];
    const float* bhhB = (const float*)d_in[10];
    const float* dw   = (const float*)d_in[11];
    const float* db   = (const float*)d_in[12];
    float* out = (float*)d_out;

    char* ws = (char*)d_ws;
    unsigned short* xs   = (unsigned short*)(ws);                     // 16 MiB bf16 frag-linear
    unsigned short* hvec = (unsigned short*)(ws + (16u << 20));       // 64 MiB bf16 (Bp,T,256)
    float* pooled        = (float*)(ws + (16u << 20) + (64u << 20));  // 1 MiB fp32 (Bp,256)

    k_proj<<<dim3(64, 128), 256, 0, stream>>>(X, Wt, bt, xs);
    k_lstm<<<128, 512, 0, stream>>>(xs, WihF, WhhF, bihF, bhhF,
                                        WihB, WhhB, bihB, bhhB, hvec);
    k_attn<<<1024, 256, 0, stream>>>(hvec, pooled);
    k_norm<<<16, 256, 0, stream>>>(pooled, dw, db, out);
}